// Round 13
// baseline (346.570 us; speedup 1.0000x reference)
//
#include <hip/hip_runtime.h>
#include <hip/hip_bf16.h>

// LSTM B=8192,T=512,I=3,H=25 + linear[H->1], bf16 MFMA 16x16x32.
// R25: INTERLEAVED DUAL-CHAIN INTERVALS. R24 post-mortem: rotated phases
// were dense(acts ~285cy)/sparse(mfma ~50cy) and every barrier syncs to the
// slow side -> 1130cy/step. Identity from R12-R24: with in-phase blocks,
// period/step = per-SIMD issue + exposure/chains_per_CU; total trans is
// invariant and chains/CU is capped at 2 -> every wave/block shuffle lands
// at ~457cy/step. Remaining lever: hide the exposure INSIDE one wave's
// stream with uniformly dense intervals. Each interval (one barrier):
//   ds_read chain Y's frag FIRST (120cy latency)
//   acts burst of chain X (~224cy trans issue - covers the read)
//   write h_X; x-insert + 2 MFMA for Y; lgkmcnt(0); s_barrier
// Roles alternate each interval. Separate __shared__ arrays per chain so
// X-writes can't alias-block Y-reads (R23's serialization). Single buffer
// per chain (read-Y and write-Y are in different intervals). First interval
// acts on zero acc/zero c -> writes exact h=0 over the zeroed buffer (no
// prologue). 256 blocks x 4 waves = 1 wave/SIMD, 1 block/CU: no co-resident
// phase lottery at all.
// Model: interval = issue ~300 + tail ~100 = ~400cy; 1025 intervals ~170us.
// Kept: reg A-frags w/ -K1/-K2 prescale, frag-linear LDS, pad/scrap-slot
// writes, merged-denominator c-update, v2f pk glue, x reg ping-pong,
// lgkmcnt-only barrier.

#define TSTEPS 512
#define ISZ 3
#define HSZ 25

typedef __attribute__((ext_vector_type(8))) short bf16x8;
typedef __attribute__((ext_vector_type(4))) float f32x4;
typedef __attribute__((ext_vector_type(4))) int i32x4;
typedef __attribute__((ext_vector_type(2))) float v2f;

__device__ __forceinline__ unsigned short bf16_bits(float v) {
    return __builtin_bit_cast(unsigned short, __float2bfloat16(v));
}
__device__ __forceinline__ unsigned int pack_bf16(float lo, float hi) {
    return ((unsigned int)bf16_bits(hi) << 16) | (unsigned int)bf16_bits(lo);
}
__device__ __forceinline__ v2f rcp2(v2f v) {
    return (v2f){__builtin_amdgcn_rcpf(v.x), __builtin_amdgcn_rcpf(v.y)};
}

__global__ __launch_bounds__(256, 1) void lstm_mfma(
    const float* __restrict__ x,      // [B, T, I]
    const float* __restrict__ w_ih,   // [4H, I]
    const float* __restrict__ w_hh,   // [4H, H]
    const float* __restrict__ b_ih,   // [4H]
    const float* __restrict__ b_hh,   // [4H]
    const float* __restrict__ w_lin,  // [1, H]
    const float* __restrict__ b_lin,  // [1]
    float* __restrict__ out)          // [B, 1]
{
    // frag-linear: short idx (k,n) = (k>>3)*128 + n*8 + (k&7); idx 0..511
    // real frag (k<32); 512..767 scrap for row-block-7 writes (kw<=35).
    // SEPARATE arrays per chain -> no may-alias between X-write and Y-read.
    __shared__ short hba[768];
    __shared__ short hbb[768];
    __shared__ float outred[4][2][16];

    const int tid  = threadIdx.x;
    const int w    = tid >> 6;        // wave 0..3, one per SIMD
    const int lane = tid & 63;
    const int n    = lane & 15;       // batch col within chain
    const int q    = lane >> 4;       // quad -> k-slots 8q..8q+7
    const int b0   = blockIdx.x * 32; // chain A: b0.., chain B: b0+16..

    const float K1 = 1.442695040888963f;   // log2 e
    const float K2 = 2.885390081777927f;   // 2 log2 e

    // zero both buffers (h(0)=0): 2 x 1536 B
    if (tid < 96) {
        ((int4*)hba)[tid] = (int4){0, 0, 0, 0};
        ((int4*)hbb)[tid] = (int4){0, 0, 0, 0};
    }

    // ---- A fragments for row-blocks jbA=w, jbB=w+4 (shared by chains) ----
    // Within a row-block: MFMA row rr=n -> unit 4*jb + (n>>2), gate n&3.
    // k map: 0..2 w_ih, 3 bias, 4..28 w_hh col k-4, 29..31 pad.
    bf16x8 afA, afB;
    {
        const int g = n & 3, us = n >> 2;
        const int uA = 4 * w + us;            // <= 15, always valid
        const int uB = 4 * (w + 4) + us;      // 16..31, guard < 25
        #pragma unroll
        for (int j = 0; j < 8; ++j) {
            const int k = q * 8 + j;
            float vA = 0.f, vB = 0.f;
            {
                const int orow = g * HSZ + uA;
                if (k < ISZ)            vA = w_ih[orow * ISZ + k];
                else if (k == ISZ)      vA = b_ih[orow] + b_hh[orow];
                else if (k < 4 + HSZ)   vA = w_hh[orow * HSZ + (k - 4)];
                vA *= (g == 2) ? -K2 : -K1;
            }
            if (uB < HSZ) {
                const int orow = g * HSZ + uB;
                if (k < ISZ)            vB = w_ih[orow * ISZ + k];
                else if (k == ISZ)      vB = b_ih[orow] + b_hh[orow];
                else if (k < 4 + HSZ)   vB = w_hh[orow * HSZ + (k - 4)];
                vB *= (g == 2) ? -K2 : -K1;
            }
            afA[j] = (short)bf16_bits(vA);
            afB[j] = (short)bf16_bits(vB);
        }
    }

    // ---- write slots: unit u=4jb+q -> k=u+4 (pads/scrap land harmlessly) --
    const int uwA = 4 * w + q;                 // <= 15
    const int uwB = 4 * (w + 4) + q;           // 16..31 (>=25 -> pad/scrap)
    const int kwA = uwA + 4, kwB = uwB + 4;    // kwB <= 35 -> scrap region
    const int woffA = (kwA >> 3) * 128 + n * 8 + (kwA & 7);
    const int woffB = (kwB >> 3) * 128 + n * 8 + (kwB & 7);
    const int rdoff = lane * 8;

    const f32x4 zc = {0.f, 0.f, 0.f, 0.f};
    v2f cA = {0.f, 0.f}, hA = {0.f, 0.f};
    v2f cB = {0.f, 0.f}, hB = {0.f, 0.f};
    f32x4 acAA = zc, acAB = zc;    // chain A accs (row-blocks A,B)
    f32x4 acBA = zc, acBB = zc;    // chain B accs

    // ---- x prefetch: per chain 3 x float4 per 4-step group ----
    const float* __restrict__ xga = x + (size_t)(b0 + n) * (TSTEPS * ISZ);
    const float* __restrict__ xgb = x + (size_t)(b0 + 16 + n) * (TSTEPS * ISZ);
    float4 A0 = ((const float4*)xga)[0];
    float4 A1 = ((const float4*)xga)[1];
    float4 A2 = ((const float4*)xga)[2];
    float4 B0 = ((const float4*)xgb)[0];
    float4 B1 = ((const float4*)xgb)[1];
    float4 B2 = ((const float4*)xgb)[2];

    __syncthreads();   // zeros visible (drains first prefetch once - ok)

    // acts for chain X from held accs; update c,h; write h to X's buffer.
    // Identical math to R19 (passed, absmax .0156). Zero acc/zero c -> h=0.
    auto acts = [&](const f32x4& aA, const f32x4& aB, v2f& c, v2f& h,
                    short* __restrict__ wbuf) {
        const v2f e0 = {__builtin_amdgcn_exp2f(aA[0]), __builtin_amdgcn_exp2f(aB[0])};
        const v2f e1 = {__builtin_amdgcn_exp2f(aA[1]), __builtin_amdgcn_exp2f(aB[1])};
        const v2f e2 = {__builtin_amdgcn_exp2f(fminf(aA[2], 126.f)),
                        __builtin_amdgcn_exp2f(fminf(aB[2], 126.f))};
        const v2f e3 = {__builtin_amdgcn_exp2f(aA[3]), __builtin_amdgcn_exp2f(aB[3])};
        const v2f one = {1.f, 1.f};
        const v2f s0 = e0 + one, s1 = e1 + one, s2 = e2 + one, m2 = one - e2;
        const v2f p02 = s0 * s2;
        const v2f num = c * p02 + m2 * s1;     // merged-denominator c-update
        const v2f den = p02 * s1;
        c = num * rcp2(den);
        const v2f ec = {__builtin_amdgcn_exp2f(fminf(-K2 * c.x, 126.f)),
                        __builtin_amdgcn_exp2f(fminf(-K2 * c.y, 126.f))};
        const v2f hden = (e3 + one) * (ec + one);
        h = (one - ec) * rcp2(hden);
        wbuf[woffA] = (short)bf16_bits(h.x);
        wbuf[woffB] = (short)bf16_bits(h.y);   // pad/scrap-slot trick
    };

    // one interval: read Y's frag FIRST (latency hides under acts X), acts X
    // + write, then x-insert + MFMAs for Y, one barrier.
    auto interval = [&](const short* __restrict__ rbuf, short* __restrict__ wbuf,
                        float y0, float y1, float y2,
                        f32x4& yA, f32x4& yB,
                        const f32x4& xA, const f32x4& xB,
                        v2f& c, v2f& h) {
        bf16x8 frag = *(const bf16x8*)(rbuf + rdoff);   // ds_read_b128 early
        acts(xA, xB, c, h, wbuf);                       // ~224cy trans burst
        i32x4 fi = __builtin_bit_cast(i32x4, frag);
        const int px0 = (int)pack_bf16(y0, y1);
        const int px1 = (int)pack_bf16(y2, 1.0f);
        fi[0] = (q == 0) ? px0 : fi[0];
        fi[1] = (q == 0) ? px1 : fi[1];
        const bf16x8 f2 = __builtin_bit_cast(bf16x8, fi);
        yA = __builtin_amdgcn_mfma_f32_16x16x32_bf16(afA, f2, zc, 0, 0, 0);
        yB = __builtin_amdgcn_mfma_f32_16x16x32_bf16(afB, f2, zc, 0, 0, 0);
        asm volatile("s_waitcnt lgkmcnt(0)" ::: "memory");
        __builtin_amdgcn_s_barrier();
    };

    // one step k: even interval {acts A(h_A(k)), read/MFMA B(k)};
    //             odd interval  {acts B(h_B(k+1)), read/MFMA A(k)}.
    auto step = [&](float ax0, float ax1, float ax2,
                    float bx0, float bx1, float bx2) {
        interval(hbb, hba, bx0, bx1, bx2, acBA, acBB, acAA, acAB, cA, hA);
        interval(hba, hbb, ax0, ax1, ax2, acAA, acAB, acBA, acBB, cB, hB);
    };

    #pragma unroll 1
    for (int g = 0; g < 128; g += 2) {
        const int gp1 = (g + 1 < 128) ? g + 1 : 127;
        const float4* __restrict__ pA1 = (const float4*)(xga + (size_t)gp1 * 12);
        const float4* __restrict__ pB1 = (const float4*)(xgb + (size_t)gp1 * 12);
        const float4 nA0 = pA1[0], nA1 = pA1[1], nA2 = pA1[2];
        const float4 nB0 = pB1[0], nB1 = pB1[1], nB2 = pB1[2];
        step(A0.x, A0.y, A0.z, B0.x, B0.y, B0.z);
        step(A0.w, A1.x, A1.y, B0.w, B1.x, B1.y);
        step(A1.z, A1.w, A2.x, B1.z, B1.w, B2.x);
        step(A2.y, A2.z, A2.w, B2.y, B2.z, B2.w);
        const int gp2 = (g + 2 < 128) ? g + 2 : 127;
        const float4* __restrict__ pA2 = (const float4*)(xga + (size_t)gp2 * 12);
        const float4* __restrict__ pB2 = (const float4*)(xgb + (size_t)gp2 * 12);
        A0 = pA2[0]; A1 = pA2[1]; A2 = pA2[2];
        B0 = pB2[0]; B1 = pB2[1]; B2 = pB2[2];
        step(nA0.x, nA0.y, nA0.z, nB0.x, nB0.y, nB0.z);
        step(nA0.w, nA1.x, nA1.y, nB0.w, nB1.x, nB1.y);
        step(nA1.z, nA1.w, nA2.x, nB1.z, nB1.w, nB2.x);
        step(nA2.y, nA2.z, nA2.w, nB2.y, nB2.z, nB2.w);
    }
    // final acts A: acc_A(511) -> h_A(512) (write harmless, no barrier)
    acts(acAA, acAB, cA, hA, hba);

    // ---- final linear: out[b] = sum_u w_lin[u]*h[u] + b_lin, per chain ----
    const float wlA = (uwA < HSZ) ? w_lin[uwA] : 0.f;
    const float wlB = (uwB < HSZ) ? w_lin[uwB] : 0.f;
    float v0 = wlA * hA.x + wlB * hA.y;     // chain A
    float v1 = wlA * hB.x + wlB * hB.y;     // chain B
    v0 += __shfl_xor(v0, 16);
    v1 += __shfl_xor(v1, 16);
    v0 += __shfl_xor(v0, 32);
    v1 += __shfl_xor(v1, 32);
    if (lane < 16) {
        outred[w][0][lane] = v0;
        outred[w][1][lane] = v1;
    }
    __syncthreads();
    if (tid < 32) {
        const int c2 = tid >> 4, nn = tid & 15;
        float s = b_lin[0];
        #pragma unroll
        for (int k2 = 0; k2 < 4; ++k2) s += outred[k2][c2][nn];
        out[b0 + c2 * 16 + nn] = s;
    }
}

extern "C" void kernel_launch(void* const* d_in, const int* in_sizes, int n_in,
                              void* d_out, int out_size, void* d_ws, size_t ws_size,
                              hipStream_t stream) {
    const float* x     = (const float*)d_in[0];
    const float* w_ih  = (const float*)d_in[1];
    const float* w_hh  = (const float*)d_in[2];
    const float* b_ih  = (const float*)d_in[3];
    const float* b_hh  = (const float*)d_in[4];
    const float* w_lin = (const float*)d_in[5];
    const float* b_lin = (const float*)d_in[6];
    float* out = (float*)d_out;

    lstm_mfma<<<8192 / 32, 256, 0, stream>>>(x, w_ih, w_hh, b_ih, b_hh,
                                             w_lin, b_lin, out);
}